// Round 1
// baseline (287.625 us; speedup 1.0000x reference)
//
#include <hip/hip_runtime.h>
#include <hip/hip_bf16.h>
#include <stdint.h>
#include <stddef.h>

#define HH_EPS 1e-8f

typedef __attribute__((ext_vector_type(8))) short short8;
typedef __attribute__((ext_vector_type(4))) float f32x4;

// ---------------------------------------------------------------------------
// Kernel 1: v_hat[k] = V[k] / (||V[k]|| + eps).  32 blocks x 64 threads.
// ---------------------------------------------------------------------------
__global__ void normalize_v(const float* __restrict__ V, float* __restrict__ vhat) {
    const int k = blockIdx.x;        // 0..31
    const int lane = threadIdx.x;    // 0..63, 8 floats per lane
    const float4* row = (const float4*)(V + (size_t)k * 512);
    float4 a = row[lane * 2 + 0];
    float4 b = row[lane * 2 + 1];
    float ss = a.x*a.x + a.y*a.y + a.z*a.z + a.w*a.w
             + b.x*b.x + b.y*b.y + b.z*b.z + b.w*b.w;
    #pragma unroll
    for (int off = 32; off > 0; off >>= 1) ss += __shfl_xor(ss, off);
    const float inv = 1.0f / (sqrtf(ss) + HH_EPS);
    float4* orow = (float4*)(vhat + (size_t)k * 512);
    orow[lane * 2 + 0] = make_float4(a.x*inv, a.y*inv, a.z*inv, a.w*inv);
    orow[lane * 2 + 1] = make_float4(b.x*inv, b.y*inv, b.z*inv, b.w*inv);
}

// ---------------------------------------------------------------------------
// Kernel 2: W = H_32 ... H_1.  Column j evolves independently:
//   w_j <- w_j - 2 (vhat . w_j) vhat,  k = 0..31 in order.
// One wave per column (8 elems/lane), shuffle-reduce for the dot.
// Output: W bf16 row-major [o][c] (the GEMM A operand).
// 128 blocks x 256 threads (4 waves = 4 columns per block).
// ---------------------------------------------------------------------------
__global__ void compute_w(const float* __restrict__ vhat,
                          __hip_bfloat16* __restrict__ Wb) {
    const int wave = threadIdx.x >> 6;
    const int lane = threadIdx.x & 63;
    const int j = blockIdx.x * 4 + wave;   // column index 0..511
    const int ib = lane * 8;               // rows ib..ib+7 held by this lane

    float w[8];
    #pragma unroll
    for (int r = 0; r < 8; r++) w[r] = (ib + r == j) ? 1.0f : 0.0f;

    for (int k = 0; k < 32; k++) {
        const float4* vp = (const float4*)(vhat + (size_t)k * 512 + ib);
        float4 v0 = vp[0], v1 = vp[1];
        float v[8] = {v0.x, v0.y, v0.z, v0.w, v1.x, v1.y, v1.z, v1.w};
        float d = 0.0f;
        #pragma unroll
        for (int r = 0; r < 8; r++) d += v[r] * w[r];
        #pragma unroll
        for (int off = 32; off > 0; off >>= 1) d += __shfl_xor(d, off);
        const float t = 2.0f * d;
        #pragma unroll
        for (int r = 0; r < 8; r++) w[r] -= t * v[r];
    }
    #pragma unroll
    for (int r = 0; r < 8; r++)
        Wb[(size_t)(ib + r) * 512 + j] = __float2bfloat16(w[r]);
}

// ---------------------------------------------------------------------------
// Kernel 3: out[b] = W @ x[b].  M=512 (o), K=512 (c), N=4096 (hw), 16 batches.
// 128x128 tile, BK=32, 256 threads = 4 waves in 2x2, each wave 4x4 MFMA
// 16x16x32 bf16 tiles.  x is [K][N] row-major -> B fragments need k-contiguity,
// so B is transpose-staged through registers with fp32->bf16 conversion into a
// [n][k] LDS tile (row stride 40 bf16 = 80 B: 16B-aligned, conflict-free).
// ---------------------------------------------------------------------------
#define BM 128
#define BN 128
#define BK 32
#define CDIM 512
#define SDIM 4096
#define BROW 40   // padded Blds row stride in bf16 (32 + 8)

__global__ __launch_bounds__(256, 2) void hh_gemm(
    const float* __restrict__ x,
    const __hip_bfloat16* __restrict__ Wb,
    float* __restrict__ out)
{
    __shared__ __attribute__((aligned(16))) __hip_bfloat16 Alds[BM * BK];    // [m][k], row stride 32
    __shared__ __attribute__((aligned(16))) __hip_bfloat16 Blds[BN * BROW];  // [n][k], row stride 40

    const int tid  = threadIdx.x;
    const int wave = tid >> 6, lane = tid & 63;
    const int quad = lane >> 4, l16 = lane & 15;
    const int wm = wave >> 1, wn = wave & 1;

    const int mt = blockIdx.x;   // 0..3   (fastest: m-tiles sharing an x-tile co-resident)
    const int nt = blockIdx.y;   // 0..31
    const int b  = blockIdx.z;   // 0..15
    const int m0 = mt * BM, n0 = nt * BN;

    const float* xb = x + (size_t)b * CDIM * SDIM;

    f32x4 acc[4][4];
    #pragma unroll
    for (int i = 0; i < 4; i++)
        #pragma unroll
        for (int jj = 0; jj < 4; jj++) {
            f32x4 z = {0.0f, 0.0f, 0.0f, 0.0f};
            acc[i][jj] = z;
        }

    for (int kt = 0; kt < CDIM / BK; kt++) {
        const int k0 = kt * BK;
        __syncthreads();   // previous compute done before overwriting LDS

        // ---- stage A: W[m0..m0+127][k0..k0+31] bf16, 2 x 16B chunks/thread ----
        #pragma unroll
        for (int c = 0; c < 2; c++) {
            const int chunk = c * 256 + tid;          // 0..511
            const int row = chunk >> 2, seg = chunk & 3;
            const short8 av = *(const short8*)(Wb + (size_t)(m0 + row) * CDIM + k0 + seg * 8);
            *(short8*)(&Alds[chunk * 8]) = av;        // contiguous [row][k]
        }

        // ---- gather + transpose + convert B: x[k0..k0+31][n0..n0+127] ----
        #pragma unroll
        for (int c = 0; c < 2; c++) {
            const int u = c * 256 + tid;              // 0..511
            const int n = u & 127, kg = u >> 7;       // kg in 0..3 (8 k's each)
            const float* gp = xb + (size_t)(k0 + kg * 8) * SDIM + n0 + n;
            float f[8];
            #pragma unroll
            for (int jj = 0; jj < 8; jj++) f[jj] = gp[(size_t)jj * SDIM];
            short8 pk;
            #pragma unroll
            for (int jj = 0; jj < 8; jj++) {
                __hip_bfloat16 h = __float2bfloat16(f[jj]);
                pk[jj] = *(short*)&h;
            }
            *(short8*)(&Blds[n * BROW + kg * 8]) = pk;
        }
        __syncthreads();

        // ---- compute: 4 A-frags, 4 B-frags, 16 MFMAs ----
        short8 af[4], bfr[4];
        #pragma unroll
        for (int mi = 0; mi < 4; mi++)
            af[mi] = *(const short8*)(&Alds[(wm * 64 + mi * 16 + l16) * BK + quad * 8]);
        #pragma unroll
        for (int ni = 0; ni < 4; ni++)
            bfr[ni] = *(const short8*)(&Blds[(wn * 64 + ni * 16 + l16) * BROW + quad * 8]);
        #pragma unroll
        for (int mi = 0; mi < 4; mi++)
            #pragma unroll
            for (int ni = 0; ni < 4; ni++)
                acc[mi][ni] = __builtin_amdgcn_mfma_f32_16x16x32_bf16(
                    af[mi], bfr[ni], acc[mi][ni], 0, 0, 0);
    }

    // ---- epilogue: D[row][col], col = l16, row = quad*4 + r ----
    float* ob = out + (size_t)b * CDIM * SDIM;
    #pragma unroll
    for (int mi = 0; mi < 4; mi++) {
        #pragma unroll
        for (int ni = 0; ni < 4; ni++) {
            const int col = n0 + wn * 64 + ni * 16 + l16;
            #pragma unroll
            for (int r = 0; r < 4; r++) {
                const int row = m0 + wm * 64 + mi * 16 + quad * 4 + r;
                ob[(size_t)row * SDIM + col] = acc[mi][ni][r];
            }
        }
    }
}

// ---------------------------------------------------------------------------
extern "C" void kernel_launch(void* const* d_in, const int* in_sizes, int n_in,
                              void* d_out, int out_size, void* d_ws, size_t ws_size,
                              hipStream_t stream) {
    const float* x = (const float*)d_in[0];   // [16, 512, 64, 64]
    const float* V = (const float*)d_in[1];   // [32, 512]
    float* out = (float*)d_out;               // [16, 512, 64, 64] fp32

    float* vhat = (float*)d_ws;                                   // 64 KB
    __hip_bfloat16* Wb = (__hip_bfloat16*)((char*)d_ws + 65536);  // 512 KB

    normalize_v<<<32, 64, 0, stream>>>(V, vhat);
    compute_w<<<128, 256, 0, stream>>>(vhat, Wb);
    dim3 grid(4, 32, 16);  // (m-tile, n-tile, batch)
    hh_gemm<<<grid, 256, 0, stream>>>(x, Wb, out);
}